// Round 3
// baseline (46434.067 us; speedup 1.0000x reference)
//
#include <hip/hip_runtime.h>
#include <hip/hip_bf16.h>
#include <stdint.h>

typedef __bf16 bf16;
typedef __attribute__((ext_vector_type(8))) __bf16 bf16x8;
typedef __attribute__((ext_vector_type(4))) float f32x4;

#define MFMA_B16(a,b,c) __builtin_amdgcn_mfma_f32_16x16x32_bf16((a),(b),(c),0,0,0)

// problem dims
#define BATCH  1024
#define NSTEPS 1024
#define OBS    32
#define ACTD   8
#define WIDTH  512
#define ROWS   16
#define NWG    (BATCH/ROWS)  // 64
#define OUTS   ((NSTEPS+1)*OBS)
#define K0     128           // [y_hi 32 | y_lo 32 | act 8 | pad -> 128]

// ws layout (bf16 element offsets)
#define W0P_OFF 0
#define W0P_N   (WIDTH*K0)
#define W1_OFF  (W0P_OFF + W0P_N)
#define WBIG_N  (WIDTH*WIDTH)
#define W2_OFF  (W1_OFF + WBIG_N)
#define W3_OFF  (W2_OFF + WBIG_N)
#define W3_N    (OBS*WIDTH)
#define TAU_OFF (W3_OFF + W3_N)

#define NSLOT 3

// async DMA global->LDS: 16B/lane, LDS dest = uniform base + lane*16 (linear)
#define GLL(SRC, DST) __builtin_amdgcn_global_load_lds( \
    (const __attribute__((address_space(1))) unsigned int*)(const void*)(SRC), \
    (__attribute__((address_space(3))) unsigned int*)(void*)(DST), 16, 0, 0)

// stage a 4KB piece = 4 chunks of 1KB; per-lane source is pre-permuted so the
// LDS image is already in B-fragment read order (read offset = lane*16, conflict-free)
__device__ __forceinline__ void stage4(const bf16* src, int strideElems, bf16* dst){
  GLL(src,                 dst);
  GLL(src +   strideElems, dst + 512);
  GLL(src + 2*strideElems, dst + 1024);
  GLL(src + 3*strideElems, dst + 1536);
}

// counted vmcnt: all but newest 4 DMA ops have landed; never drain to 0 in loop
#define WAITVM4() do{ asm volatile("s_waitcnt vmcnt(4)" ::: "memory"); \
                      __builtin_amdgcn_sched_barrier(0); }while(0)
// activation barrier: drain LDS ops only — DMA stream stays in flight across it
#define LBAR() do{ asm volatile("s_waitcnt lgkmcnt(0)" ::: "memory"); \
                   __builtin_amdgcn_s_barrier(); \
                   __builtin_amdgcn_sched_barrier(0); }while(0)

__global__ void setup_kernel(const float* __restrict__ W0, const float* __restrict__ W1,
                             const float* __restrict__ W2, const float* __restrict__ W3,
                             const int* __restrict__ tau, bf16* __restrict__ wsb){
  int i = blockIdx.x*blockDim.x + threadIdx.x;
  int stride = gridDim.x*blockDim.x;
  for (int idx=i; idx<W0P_N; idx+=stride){
    int r = idx >> 7, c = idx & 127;
    float v = 0.0f;
    if (c < 32)      v = W0[r*40 + c];
    else if (c < 64) v = W0[r*40 + (c-32)];
    else if (c < 72) v = W0[r*40 + 32 + (c-64)];
    wsb[W0P_OFF+idx] = (bf16)v;
  }
  for (int idx=i; idx<WBIG_N; idx+=stride) wsb[W1_OFF+idx] = (bf16)W1[idx];
  for (int idx=i; idx<WBIG_N; idx+=stride) wsb[W2_OFF+idx] = (bf16)W2[idx];
  for (int idx=i; idx<W3_N;  idx+=stride) wsb[W3_OFF+idx] = (bf16)W3[idx];
  if (i==0){
    int ti = *tau;
    float tf;
    if (ti >= -1000000 && ti <= 1000000) tf = (float)ti;
    else { union {int q; float f;} u; u.q = ti; tf = u.f; }
    *(float*)(wsb + TAU_OFF) = tf;
  }
}

__device__ __forceinline__ float leaky(float v){ return v < 0.0f ? 0.01f*v : v; }

__global__ __launch_bounds__(512)
void ode_kernel(const float* __restrict__ init_obs, const float* __restrict__ actions,
                const float* __restrict__ b0g, const float* __restrict__ b1g,
                const float* __restrict__ b2g, const float* __restrict__ b3g,
                const bf16* __restrict__ wsb, float* __restrict__ out){
  const bf16* w0p = wsb + W0P_OFF;
  const bf16* w1  = wsb + W1_OFF;
  const bf16* w2  = wsb + W2_OFF;
  const float tauf = *(const float*)(wsb + TAU_OFF);

  __shared__ alignas(16) bf16 pieces[8][NSLOT][2048]; // 96KB per-wave 3-slot DMA ring
  __shared__ alignas(16) bf16 xin[ROWS*K0];           // 4KB
  __shared__ alignas(16) bf16 hA[ROWS*WIDTH];         // 16KB
  __shared__ alignas(16) bf16 hB[ROWS*WIDTH];         // 16KB
  __shared__ float pr[4][ROWS][OBS];                  // 8KB
  __shared__ float yS[ROWS][OBS];                     // 2KB

  const int t    = threadIdx.x;
  const int lane = t & 63;
  const int wave = t >> 6;
  const int gb0  = blockIdx.x * ROWS;
  const int am    = lane & 15;
  const int kg    = lane >> 4;
  const int crow0 = kg*4;
  const int n0    = wave*64;

  // per-lane DMA source bases, pre-permuted to fragment order:
  // chunk nt, lane l  <->  W[n0 + nt*16 + (l&15)][ kblock + (l>>4)*8 .. +8 )
  const bf16* st0 = w0p + (size_t)(n0 + am)*K0    + kg*8;
  const bf16* st1 = w1  + (size_t)(n0 + am)*WIDTH + kg*8;
  const bf16* st2 = w2  + (size_t)(n0 + am)*WIDTH + kg*8;
  const int ntb = wave >> 2;                // l3: output col-tile
  const int kc  = wave & 3;                 // l3: K-chunk of 128
  const bf16* st3 = wsb + W3_OFF + (size_t)(ntb*16 + am)*WIDTH + kc*128 + kg*8;

  bf16* const pbase = &pieces[wave][0][0];
  const int poff = lane*16;                 // linear, conflict-free b128 read

  float b0v[4], b1v[4], b2v[4];
  #pragma unroll
  for (int nt=0; nt<4; nt++){
    int col = n0 + nt*16 + am;
    b0v[nt] = b0g[col]; b1v[nt] = b1g[col]; b2v[nt] = b2g[col];
  }

  // swizzled LDS A-fragment bases
  const int swH    = (am & 15) << 3;
  const int abaseH = am*WIDTH + ((kg*8) ^ swH);
  const int abase0 = am*K0    + ((kg*8) ^ swH);

  // update-phase constants
  const int urow = t >> 5, ucol = t & 31;
  const float b3v = b3g[ucol];
  float* const outp = out + (size_t)(gb0 + urow)*OUTS + ucol;
  const int arow = (t >> 3) & 15, acol = t & 7;
  const float* const actp = actions + (size_t)(gb0 + arow)*(NSTEPS*ACTD) + acol;
  const int swU    = (urow & 15) << 3;
  const int xin_yh = urow*K0 + (ucol ^ swU);
  const int xin_yl = urow*K0 + ((ucol + 32) ^ swU);
  const int xin_ac = arow*K0 + ((64 + acol) ^ ((arow & 15) << 3));

  // ---- init ----
  {
    #pragma unroll
    for (int q=0; q<(ROWS*K0)/512; q++) xin[q*512 + t] = (bf16)0.0f;
    __syncthreads();
    float yv = init_obs[(gb0 + urow)*OBS + ucol];
    yS[urow][ucol] = yv;
    outp[0] = yv;
    bf16 yh = (bf16)yv;
    xin[xin_yh] = yh;
    xin[xin_yl] = (bf16)(yv - (float)yh);
    if (t < 128) xin[xin_ac] = (bf16)actp[0];
  }
  __syncthreads();

  // ---- prologue: issue pieces p0,p1 (l0 k=0,1) ----
  int cslot = 0, islot = 2;
  stage4(st0,      K0*16, pbase + 0*2048);
  stage4(st0 + 32, K0*16, pbase + 1*2048);

  for (int s=0; s<NSTEPS; ++s){
    const int sidx = (s+1 < NSTEPS) ? s+1 : 0;

    // ---- layer 0: xin(16xK0) @ W0p^T -> hA ----
    {
      f32x4 acc[4] = {{0,0,0,0},{0,0,0,0},{0,0,0,0},{0,0,0,0}};
      #pragma unroll
      for (int k=0; k<4; k++){
        WAITVM4();
        const bf16* pc = pbase + cslot*2048; cslot = (cslot==NSLOT-1)?0:cslot+1;
        bf16x8 a = *(const bf16x8*)&xin[abase0 ^ (k*32)];
        bf16x8 b[4];
        #pragma unroll
        for (int nt=0; nt<4; nt++)
          b[nt] = *(const bf16x8*)((const char*)pc + nt*1024 + poff);
        bf16* dq = pbase + islot*2048; islot = (islot==NSLOT-1)?0:islot+1;
        if      (k==0) stage4(st0 + 2*32, K0*16,    dq);
        else if (k==1) stage4(st0 + 3*32, K0*16,    dq);
        else if (k==2) stage4(st1,        WIDTH*16, dq);
        else           stage4(st1 + 32,   WIDTH*16, dq);
        #pragma unroll
        for (int nt=0; nt<4; nt++) acc[nt] = MFMA_B16(a, b[nt], acc[nt]);
      }
      #pragma unroll
      for (int nt=0; nt<4; nt++){
        int col = n0 + nt*16 + am;
        #pragma unroll
        for (int r=0; r<4; r++){
          int row = crow0 + r;
          hA[row*WIDTH + (col ^ ((row&15)<<3))] = (bf16)leaky(acc[nt][r] + b0v[nt]);
        }
      }
    }
    LBAR();
    float av = actp[(size_t)sidx*ACTD];   // prefetch next-step action

    // ---- layer 1: hA @ W1^T -> hB ----
    {
      f32x4 acc[4] = {{0,0,0,0},{0,0,0,0},{0,0,0,0},{0,0,0,0}};
      #pragma unroll
      for (int k=0; k<16; k++){
        WAITVM4();
        const bf16* pc = pbase + cslot*2048; cslot = (cslot==NSLOT-1)?0:cslot+1;
        bf16x8 a = *(const bf16x8*)&hA[abaseH ^ (k*32)];
        bf16x8 b[4];
        #pragma unroll
        for (int nt=0; nt<4; nt++)
          b[nt] = *(const bf16x8*)((const char*)pc + nt*1024 + poff);
        bf16* dq = pbase + islot*2048; islot = (islot==NSLOT-1)?0:islot+1;
        if      (k < 14) stage4(st1 + (k+2)*32, WIDTH*16, dq);
        else if (k ==14) stage4(st2,            WIDTH*16, dq);
        else             stage4(st2 + 32,       WIDTH*16, dq);
        #pragma unroll
        for (int nt=0; nt<4; nt++) acc[nt] = MFMA_B16(a, b[nt], acc[nt]);
      }
      #pragma unroll
      for (int nt=0; nt<4; nt++){
        int col = n0 + nt*16 + am;
        #pragma unroll
        for (int r=0; r<4; r++){
          int row = crow0 + r;
          hB[row*WIDTH + (col ^ ((row&15)<<3))] = (bf16)leaky(acc[nt][r] + b1v[nt]);
        }
      }
    }
    LBAR();

    // ---- layer 2: hB @ W2^T -> hA ----
    {
      f32x4 acc[4] = {{0,0,0,0},{0,0,0,0},{0,0,0,0},{0,0,0,0}};
      #pragma unroll
      for (int k=0; k<16; k++){
        WAITVM4();
        const bf16* pc = pbase + cslot*2048; cslot = (cslot==NSLOT-1)?0:cslot+1;
        bf16x8 a = *(const bf16x8*)&hB[abaseH ^ (k*32)];
        bf16x8 b[4];
        #pragma unroll
        for (int nt=0; nt<4; nt++)
          b[nt] = *(const bf16x8*)((const char*)pc + nt*1024 + poff);
        bf16* dq = pbase + islot*2048; islot = (islot==NSLOT-1)?0:islot+1;
        if      (k < 14) stage4(st2 + (k+2)*32, WIDTH*16, dq);
        else if (k ==14) stage4(st3,            32,       dq);  // l3 piece
        else             stage4(st0,            K0*16,    dq);  // next-step l0 p0
        #pragma unroll
        for (int nt=0; nt<4; nt++) acc[nt] = MFMA_B16(a, b[nt], acc[nt]);
      }
      #pragma unroll
      for (int nt=0; nt<4; nt++){
        int col = n0 + nt*16 + am;
        #pragma unroll
        for (int r=0; r<4; r++){
          int row = crow0 + r;
          hA[row*WIDTH + (col ^ ((row&15)<<3))] = (bf16)leaky(acc[nt][r] + b2v[nt]);
        }
      }
    }
    LBAR();

    // ---- layer 3: 16x32, K split 4-ways across waves ----
    {
      WAITVM4();
      const bf16* pc = pbase + cslot*2048; cslot = (cslot==NSLOT-1)?0:cslot+1;
      f32x4 acc = {0,0,0,0};
      #pragma unroll
      for (int kk=0; kk<4; kk++){
        int k = kc*4 + kk;
        bf16x8 a = *(const bf16x8*)&hA[abaseH ^ (k*32)];
        bf16x8 b = *(const bf16x8*)((const char*)pc + kk*1024 + poff);
        acc = MFMA_B16(a, b, acc);
      }
      bf16* dq = pbase + islot*2048; islot = (islot==NSLOT-1)?0:islot+1;
      stage4(st0 + 32, K0*16, dq);        // next-step l0 p1
      #pragma unroll
      for (int r=0; r<4; r++) pr[kc][crow0 + r][ntb*16 + am] = acc[r];
    }
    LBAR();

    // ---- update: reduce partials, Euler step, emit, reseed xin ----
    {
      float dy = pr[0][urow][ucol] + pr[1][urow][ucol]
               + pr[2][urow][ucol] + pr[3][urow][ucol] + b3v;
      float yn = yS[urow][ucol] + tauf * dy;
      yS[urow][ucol] = yn;
      outp[(size_t)(s+1)*OBS] = yn;
      bf16 yh = (bf16)yn;
      xin[xin_yh] = yh;
      xin[xin_yl] = (bf16)(yn - (float)yh);
      if (t < 128) xin[xin_ac] = (bf16)av;
    }
    LBAR();
  }
  asm volatile("s_waitcnt vmcnt(0) lgkmcnt(0)" ::: "memory");
}

extern "C" void kernel_launch(void* const* d_in, const int* in_sizes, int n_in,
                              void* d_out, int out_size, void* d_ws, size_t ws_size,
                              hipStream_t stream){
  const float* init_obs = (const float*)d_in[0];
  const float* actions  = (const float*)d_in[1];
  const float* W0 = (const float*)d_in[2];
  const float* b0 = (const float*)d_in[3];
  const float* W1 = (const float*)d_in[4];
  const float* b1 = (const float*)d_in[5];
  const float* W2 = (const float*)d_in[6];
  const float* b2 = (const float*)d_in[7];
  const float* W3 = (const float*)d_in[8];
  const float* b3 = (const float*)d_in[9];
  const int*  tau = (const int*)d_in[10];
  bf16* wsb = (bf16*)d_ws;
  float* out = (float*)d_out;

  hipLaunchKernelGGL(setup_kernel, dim3(512), dim3(256), 0, stream,
                     W0, W1, W2, W3, tau, wsb);
  hipLaunchKernelGGL(ode_kernel, dim3(NWG), dim3(512), 0, stream,
                     init_obs, actions, b0, b1, b2, b3, (const bf16*)wsb, out);
}

// Round 4
// 46112.134 us; speedup vs baseline: 1.0070x; 1.0070x over previous
//
#include <hip/hip_runtime.h>
#include <hip/hip_bf16.h>
#include <stdint.h>

typedef __bf16 bf16;
typedef __attribute__((ext_vector_type(8))) __bf16 bf16x8;
typedef __attribute__((ext_vector_type(4))) float f32x4;
typedef __attribute__((ext_vector_type(2))) unsigned int u32x2;

#define MFMA_B16(a,b,c) __builtin_amdgcn_mfma_f32_16x16x32_bf16((a),(b),(c),0,0,0)

// problem dims
#define BATCH  1024
#define NSTEPS 1024
#define OBS    32
#define ACTD   8
#define WIDTH  512
#define ROWS   16
#define NWG    (BATCH/ROWS)  // 64
#define OUTS   ((NSTEPS+1)*OBS)
#define K0     128           // [y_hi 32 | y_lo 32 | act 8 | one(=1.0)@72 | pad -> 128]

// ws layout (bf16 element offsets)
#define W0P_OFF 0
#define W0P_N   (WIDTH*K0)
#define W1_OFF  (W0P_OFF + W0P_N)
#define WBIG_N  (WIDTH*WIDTH)
#define W2_OFF  (W1_OFF + WBIG_N)
#define W3_OFF  (W2_OFF + WBIG_N)
#define W3_N    (OBS*WIDTH)
#define TAU_OFF (W3_OFF + W3_N)

// pacing waits (compiler's own dataflow waitcnts guarantee correctness;
// these keep the double-buffer cadence). Never drain to 0 in the loop.
#define WAITVM(N) do{ asm volatile("s_waitcnt vmcnt(" #N ")" ::: "memory"); }while(0)
// activation barrier: LDS-drain only
#define LBAR() do{ asm volatile("s_waitcnt lgkmcnt(0)" ::: "memory"); \
                   __builtin_amdgcn_s_barrier(); \
                   __builtin_amdgcn_sched_barrier(0); }while(0)

__global__ void setup_kernel(const float* __restrict__ W0, const float* __restrict__ b0r,
                             const float* __restrict__ W1, const float* __restrict__ W2,
                             const float* __restrict__ W3,
                             const int* __restrict__ tau, bf16* __restrict__ wsb){
  int i = blockIdx.x*blockDim.x + threadIdx.x;
  int stride = gridDim.x*blockDim.x;
  for (int idx=i; idx<W0P_N; idx+=stride){
    int r = idx >> 7, c = idx & 127;
    float v = 0.0f;
    if (c < 32)       v = W0[r*40 + c];          // y_hi
    else if (c < 64)  v = W0[r*40 + (c-32)];     // y_lo (same weights)
    else if (c < 72)  v = W0[r*40 + 32 + (c-64)];// action
    else if (c == 72) v = b0r[r];                // bias via constant-1 input
    wsb[W0P_OFF+idx] = (bf16)v;
  }
  for (int idx=i; idx<WBIG_N; idx+=stride) wsb[W1_OFF+idx] = (bf16)W1[idx];
  for (int idx=i; idx<WBIG_N; idx+=stride) wsb[W2_OFF+idx] = (bf16)W2[idx];
  for (int idx=i; idx<W3_N;  idx+=stride) wsb[W3_OFF+idx] = (bf16)W3[idx];
  if (i==0){
    int ti = *tau;
    float tf;
    if (ti >= -1000000 && ti <= 1000000) tf = (float)ti;
    else { union {int q; float f;} u; u.q = ti; tf = u.f; }
    *(float*)(wsb + TAU_OFF) = tf;
  }
}

__device__ __forceinline__ float leaky(float v){ return v < 0.0f ? 0.01f*v : v; }

__device__ __forceinline__ uint32_t pk2(float a, float b){
  union { bf16 h; uint16_t u; } ua, ub; ua.h = (bf16)a; ub.h = (bf16)b;
  return (uint32_t)ua.u | ((uint32_t)ub.u << 16);
}

// issue 16 A-frag (weight) loads: buf[nt*4+kk] = base[nt*16*rs + koff + kk*32]
__device__ __forceinline__ void issue16(const bf16* __restrict__ base, int rs, int koff,
                                        bf16x8* buf){
  #pragma unroll
  for (int nt=0; nt<4; nt++)
    #pragma unroll
    for (int kk=0; kk<4; kk++)
      buf[nt*4+kk] = *(const bf16x8*)(base + (size_t)nt*16*rs + koff + kk*32);
}

__global__ __launch_bounds__(512, 2)
void ode_kernel(const float* __restrict__ init_obs, const float* __restrict__ actions,
                const float* __restrict__ b1g, const float* __restrict__ b2g,
                const float* __restrict__ b3g,
                const bf16* __restrict__ wsb, float* __restrict__ out){
  const bf16* w0p = wsb + W0P_OFF;
  const bf16* w1  = wsb + W1_OFF;
  const bf16* w2  = wsb + W2_OFF;
  const bf16* w3  = wsb + W3_OFF;
  const float tauf = *(const float*)(wsb + TAU_OFF);

  __shared__ alignas(16) bf16 xin[ROWS*K0];      // 4KB, swizzled
  __shared__ alignas(16) bf16 hA[ROWS*WIDTH];    // 16KB, swizzled
  __shared__ alignas(16) bf16 hB[ROWS*WIDTH];    // 16KB, swizzled
  __shared__ alignas(16) float pr[8][ROWS][OBS]; // 16KB l3 K-split partials
  __shared__ float yS[ROWS][OBS];                // 2KB fp32 state
  __shared__ float b1s[WIDTH], b2s[WIDTH];       // 4KB biases

  const int t    = threadIdx.x;
  const int lane = t & 63;
  const int wave = t >> 6;          // 0..7
  const int gb0  = blockIdx.x * ROWS;
  const int fm   = lane & 15;       // A-row (out-col) / B-col (batch) / D-col (batch)
  const int fk   = lane >> 4;       // k-octet
  const int c0   = wave*64;         // wave's 64 output cols

  // per-lane weight A-frag bases
  const bf16* w0b = w0p + (size_t)(c0 + fm)*K0    + fk*8;
  const bf16* w1b = w1  + (size_t)(c0 + fm)*WIDTH + fk*8;
  const bf16* w2b = w2  + (size_t)(c0 + fm)*WIDTH + fk*8;
  const bf16* w3b = w3  + (size_t)fm*WIDTH + wave*64 + fk*8;

  // swizzled LDS B-frag (activation) bases: elem = fm*W + ((k*32+fk*8) ^ fm*8)
  const int hbase = fm*WIDTH + ((fk*8) ^ (fm*8));
  const int xbase = fm*K0    + ((fk*8) ^ (fm*8));

  // update-phase constants
  const int urow = t >> 5, ucol = t & 31;
  const float b3v = b3g[ucol];
  float* const outp = out + (size_t)(gb0 + urow)*OUTS + ucol;
  const int arow = (t >> 3) & 15, acol = t & 7;
  const float* const actp = actions + (size_t)(gb0 + arow)*(NSTEPS*ACTD) + acol;
  const int swU    = (urow & 15) << 3;
  const int xin_yh = urow*K0 + (ucol ^ swU);
  const int xin_yl = urow*K0 + ((ucol + 32) ^ swU);
  const int xin_ac = arow*K0 + ((64 + acol) ^ ((arow & 15) << 3));

  // ---- init ----
  float yv;
  {
    #pragma unroll
    for (int q=0; q<(ROWS*K0)/512; q++) xin[q*512 + t] = (bf16)0.0f;
    b1s[t] = b1g[t]; b2s[t] = b2g[t];
    __syncthreads();
    yv = init_obs[(gb0 + urow)*OBS + ucol];
    yS[urow][ucol] = yv;
    outp[0] = yv;
    bf16 yh = (bf16)yv;
    xin[xin_yh] = yh;
    xin[xin_yl] = (bf16)(yv - (float)yh);
    if (t < 128) xin[xin_ac] = (bf16)actp[0];
    if (t < 16)  xin[t*K0 + (72 ^ ((t&15)*8))] = (bf16)1.0f;  // bias-1 column
  }
  __syncthreads();   // drains vmcnt -> clean count

  bf16x8 bufA[16], bufB[16];
  // prologue: b0 = l0 weights -> A ; b1 = l1 kq0 -> B ; dummy store matches steady state
  issue16(w0b, K0, 0, bufA);
  issue16(w1b, WIDTH, 0, bufB);
  outp[0] = yv;

  for (int s=0; s<NSTEPS; ++s){
    const int sidx = (s+1 < NSTEPS) ? s+1 : 0;
    float av = actp[(size_t)sidx*ACTD];          // +1 vmem, used in update

    // ---- p0: l0 consume(bufA) ; issue b2 = l1 kq1 -> A ----
    {
      bf16x8 h8[4];
      #pragma unroll
      for (int kk=0; kk<4; kk++) h8[kk] = *(const bf16x8*)&xin[xbase ^ (kk*32)];
      WAITVM(18);
      f32x4 acc[4] = {{0,0,0,0},{0,0,0,0},{0,0,0,0},{0,0,0,0}};
      #pragma unroll
      for (int kk=0; kk<4; kk++)
        #pragma unroll
        for (int nt=0; nt<4; nt++) acc[nt] = MFMA_B16(bufA[nt*4+kk], h8[kk], acc[nt]);
      issue16(w1b, WIDTH, 128, bufA);
      #pragma unroll
      for (int nt=0; nt<4; nt++){                 // bias already folded; leaky + pack
        int ob = c0 + nt*16 + fk*4;
        u32x2 pw = { pk2(leaky(acc[nt][0]), leaky(acc[nt][1])),
                     pk2(leaky(acc[nt][2]), leaky(acc[nt][3])) };
        *(u32x2*)&hA[fm*WIDTH + (ob ^ (fm*8))] = pw;
      }
    }
    LBAR();  // BAR1: hA ready

    // ---- l1: p1..p4 ----
    f32x4 acc1[4] = {{0,0,0,0},{0,0,0,0},{0,0,0,0},{0,0,0,0}};
    #define L1P(KQ, WN, BUF, ISSUE) { \
      bf16x8 h8[4]; \
      _Pragma("unroll") \
      for (int kk=0; kk<4; kk++) h8[kk] = *(const bf16x8*)&hA[hbase ^ ((KQ*4+kk)*32)]; \
      WAITVM(WN); \
      _Pragma("unroll") \
      for (int kk=0; kk<4; kk++) \
        _Pragma("unroll") \
        for (int nt=0; nt<4; nt++) acc1[nt] = MFMA_B16(BUF[nt*4+kk], h8[kk], acc1[nt]); \
      ISSUE; }
    L1P(0, 18, bufB, issue16(w1b, WIDTH, 256, bufB))   // p1: b3 = l1 kq2
    L1P(1, 16, bufA, issue16(w1b, WIDTH, 384, bufA))   // p2: b4 = l1 kq3
    L1P(2, 16, bufB, issue16(w2b, WIDTH, 0,   bufB))   // p3: b5 = l2 kq0
    L1P(3, 16, bufA, issue16(w2b, WIDTH, 128, bufA))   // p4: b6 = l2 kq1
    #undef L1P
    #pragma unroll
    for (int nt=0; nt<4; nt++){
      int ob = c0 + nt*16 + fk*4;
      f32x4 bv = *(const f32x4*)&b1s[ob];
      u32x2 pw = { pk2(leaky(acc1[nt][0]+bv[0]), leaky(acc1[nt][1]+bv[1])),
                   pk2(leaky(acc1[nt][2]+bv[2]), leaky(acc1[nt][3]+bv[3])) };
      *(u32x2*)&hB[fm*WIDTH + (ob ^ (fm*8))] = pw;
    }
    LBAR();  // BAR2: hB ready

    // ---- l2: p5..p8 ----
    f32x4 acc2[4] = {{0,0,0,0},{0,0,0,0},{0,0,0,0},{0,0,0,0}};
    #define L2P(KQ, WN, BUF, ISSUE) { \
      bf16x8 h8[4]; \
      _Pragma("unroll") \
      for (int kk=0; kk<4; kk++) h8[kk] = *(const bf16x8*)&hB[hbase ^ ((KQ*4+kk)*32)]; \
      WAITVM(WN); \
      _Pragma("unroll") \
      for (int kk=0; kk<4; kk++) \
        _Pragma("unroll") \
        for (int nt=0; nt<4; nt++) acc2[nt] = MFMA_B16(BUF[nt*4+kk], h8[kk], acc2[nt]); \
      ISSUE; }
    L2P(0, 16, bufB, issue16(w2b, WIDTH, 256, bufB))   // p5: b7 = l2 kq2
    L2P(1, 16, bufA, issue16(w2b, WIDTH, 384, bufA))   // p6: b8 = l2 kq3
    // p7: consume b7; issue b9 = l3 (4 loads) -> bufB[0..3]
    L2P(2, 16, bufB,
        { _Pragma("unroll")
          for (int n2=0; n2<2; n2++)
            _Pragma("unroll")
            for (int kk=0; kk<2; kk++)
              bufB[n2*2+kk] = *(const bf16x8*)(w3b + (size_t)n2*16*WIDTH + kk*32); })
    // p8: consume b8; issue b0' = next-step l0 -> bufA
    L2P(3, 4, bufA, issue16(w0b, K0, 0, bufA))
    #undef L2P
    #pragma unroll
    for (int nt=0; nt<4; nt++){
      int ob = c0 + nt*16 + fk*4;
      f32x4 bv = *(const f32x4*)&b2s[ob];
      u32x2 pw = { pk2(leaky(acc2[nt][0]+bv[0]), leaky(acc2[nt][1]+bv[1])),
                   pk2(leaky(acc2[nt][2]+bv[2]), leaky(acc2[nt][3]+bv[3])) };
      *(u32x2*)&hA[fm*WIDTH + (ob ^ (fm*8))] = pw;
    }
    LBAR();  // BAR3: hA (= h2) ready

    // ---- p9: l3 (K split 8 ways across waves); issue b1' = l1 kq0 -> bufB ----
    {
      bf16x8 h8[2];
      #pragma unroll
      for (int kk=0; kk<2; kk++)
        h8[kk] = *(const bf16x8*)&hA[hbase ^ ((wave*2+kk)*32)];
      WAITVM(16);
      f32x4 a3[2] = {{0,0,0,0},{0,0,0,0}};
      #pragma unroll
      for (int kk=0; kk<2; kk++){
        a3[0] = MFMA_B16(bufB[0*2+kk], h8[kk], a3[0]);
        a3[1] = MFMA_B16(bufB[1*2+kk], h8[kk], a3[1]);
      }
      issue16(w1b, WIDTH, 0, bufB);
      *(f32x4*)&pr[wave][fm][fk*4]      = a3[0];
      *(f32x4*)&pr[wave][fm][16 + fk*4] = a3[1];
    }
    LBAR();  // BAR4: pr ready

    // ---- update ----
    {
      float dy = b3v;
      #pragma unroll
      for (int j=0; j<8; j++) dy += pr[j][urow][ucol];
      float yn = yS[urow][ucol] + tauf * dy;
      yS[urow][ucol] = yn;
      outp[(size_t)(s+1)*OBS] = yn;
      bf16 yh = (bf16)yn;
      xin[xin_yh] = yh;
      xin[xin_yl] = (bf16)(yn - (float)yh);
      if (t < 128) xin[xin_ac] = (bf16)av;
    }
    LBAR();  // BAR5: xin ready
  }
  asm volatile("s_waitcnt vmcnt(0) lgkmcnt(0)" ::: "memory");
}

extern "C" void kernel_launch(void* const* d_in, const int* in_sizes, int n_in,
                              void* d_out, int out_size, void* d_ws, size_t ws_size,
                              hipStream_t stream){
  const float* init_obs = (const float*)d_in[0];
  const float* actions  = (const float*)d_in[1];
  const float* W0 = (const float*)d_in[2];
  const float* b0 = (const float*)d_in[3];
  const float* W1 = (const float*)d_in[4];
  const float* b1 = (const float*)d_in[5];
  const float* W2 = (const float*)d_in[6];
  const float* b2 = (const float*)d_in[7];
  const float* W3 = (const float*)d_in[8];
  const float* b3 = (const float*)d_in[9];
  const int*  tau = (const int*)d_in[10];
  bf16* wsb = (bf16*)d_ws;
  float* out = (float*)d_out;

  hipLaunchKernelGGL(setup_kernel, dim3(512), dim3(256), 0, stream,
                     W0, b0, W1, W2, W3, tau, wsb);
  hipLaunchKernelGGL(ode_kernel, dim3(NWG), dim3(512), 0, stream,
                     init_obs, actions, b1, b2, b3, (const bf16*)wsb, out);
}

// Round 5
// 30483.035 us; speedup vs baseline: 1.5233x; 1.5127x over previous
//
#include <hip/hip_runtime.h>
#include <hip/hip_bf16.h>
#include <stdint.h>

typedef __bf16 bf16;
typedef __attribute__((ext_vector_type(8))) __bf16 bf16x8;
typedef __attribute__((ext_vector_type(4))) float f32x4;
typedef __attribute__((ext_vector_type(2))) unsigned int u32x2;

#define MFMA_B16(a,b,c) __builtin_amdgcn_mfma_f32_16x16x32_bf16((a),(b),(c),0,0,0)

// problem dims
#define BATCH  1024
#define NSTEPS 1024
#define OBS    32
#define ACTD   8
#define WIDTH  512
#define ROWS   16
#define OUTS   ((NSTEPS+1)*OBS)
#define K0     128   // [y_hi 32 | y_lo 32 | act 8 | one@72 | pad -> 128]

// ws layout (bf16 element offsets)
#define W0P_OFF 0
#define W0P_N   (WIDTH*K0)          // 65536
#define W1_OFF  (W0P_OFF + W0P_N)
#define WBIG_N  (WIDTH*WIDTH)       // 262144
#define W2_OFF  (W1_OFF + WBIG_N)
#define W3_OFF  (W2_OFF + WBIG_N)
#define W3_N    (OBS*WIDTH)         // 16384
#define TAU_OFF (W3_OFF + W3_N)     // fp32 here (even offset)
// mailboxes: 64 groups x 3 hops x 4 members x (16 batch x 128 cols) bf16
#define MB_OFF  606720
#define MB_N    (64*3*4*2048)       // 1,572,864 elems
// flags: int32, one 64B line per (group,hop,member)
#define FLAG_DW_IDX (((MB_OFF + MB_N)/2) + 64)   // dword offset from ws base
#define NFLAG   (64*3*4*16)

#define LBAR() do{ asm volatile("s_waitcnt lgkmcnt(0)" ::: "memory"); \
                   __builtin_amdgcn_s_barrier(); \
                   __builtin_amdgcn_sched_barrier(0); }while(0)

__global__ void setup_kernel(const float* __restrict__ W0, const float* __restrict__ b0r,
                             const float* __restrict__ W1, const float* __restrict__ W2,
                             const float* __restrict__ W3,
                             const int* __restrict__ tau, bf16* __restrict__ wsb){
  int i = blockIdx.x*blockDim.x + threadIdx.x;
  int stride = gridDim.x*blockDim.x;
  for (int idx=i; idx<W0P_N; idx+=stride){
    int r = idx >> 7, c = idx & 127;
    float v = 0.0f;
    if (c < 32)       v = W0[r*40 + c];           // y_hi
    else if (c < 64)  v = W0[r*40 + (c-32)];      // y_lo (same weights)
    else if (c < 72)  v = W0[r*40 + 32 + (c-64)]; // action
    else if (c == 72) v = b0r[r];                 // bias via constant-1 input col
    wsb[W0P_OFF+idx] = (bf16)v;
  }
  for (int idx=i; idx<WBIG_N; idx+=stride) wsb[W1_OFF+idx] = (bf16)W1[idx];
  for (int idx=i; idx<WBIG_N; idx+=stride) wsb[W2_OFF+idx] = (bf16)W2[idx];
  for (int idx=i; idx<W3_N;  idx+=stride) wsb[W3_OFF+idx] = (bf16)W3[idx];
  int* flags = ((int*)wsb) + FLAG_DW_IDX;
  for (int idx=i; idx<NFLAG; idx+=stride) flags[idx] = 0;
  if (i==0){
    int ti = *tau;
    float tf;
    if (ti >= -1000000 && ti <= 1000000) tf = (float)ti;
    else { union {int q; float f;} u; u.q = ti; tf = u.f; }
    *(float*)(wsb + TAU_OFF) = tf;
  }
}

__device__ __forceinline__ float leaky(float v){ return v < 0.0f ? 0.01f*v : v; }

__device__ __forceinline__ uint32_t pk2(float a, float b){
  union { bf16 h; uint16_t u; } ua, ub; ua.h = (bf16)a; ub.h = (bf16)b;
  return (uint32_t)ua.u | ((uint32_t)ub.u << 16);
}

__global__ __launch_bounds__(512, 2)
void ode_kernel(const float* __restrict__ init_obs, const float* __restrict__ actions,
                const float* __restrict__ b1g, const float* __restrict__ b2g,
                const float* __restrict__ b3g,
                bf16* __restrict__ wsrw, float* __restrict__ out){
  const bf16* w0g = wsrw + W0P_OFF;
  const bf16* w1g = wsrw + W1_OFF;
  const bf16* w2g = wsrw + W2_OFF;
  const bf16* w3g = wsrw + W3_OFF;
  bf16* mbb = wsrw + MB_OFF;
  int* flags = ((int*)wsrw) + FLAG_DW_IDX;
  const float tauf = *(const float*)(wsrw + TAU_OFF);

  __shared__ alignas(16) bf16 w0s[32*512];     // 32KB pre-swizzled W0 quarter
  __shared__ alignas(16) bf16 w3s[32*512];     // 32KB pre-swizzled W3 (full)
  __shared__ alignas(16) bf16 hF0[ROWS*WIDTH]; // 16KB full-activation buffer A
  __shared__ alignas(16) bf16 hF1[ROWS*WIDTH]; // 16KB full-activation buffer B
  __shared__ alignas(16) bf16 xin[ROWS*K0];    // 4KB layer-0 input
  __shared__ alignas(16) float pr[8][16][36];  // 18KB l3 partials (+pad: no bank conflict)
  __shared__ float yS[ROWS][OBS];              // 2KB fp32 state
  __shared__ int sdead;

  const int t    = threadIdx.x;
  const int lane = t & 63;
  const int wave = t >> 6;          // 0..7
  const int fm   = lane & 15;       // A row sel / D col (batch)
  const int fk   = lane >> 4;       // k-octet / D row group
  const int b    = blockIdx.x;
  const int xcd  = b & 7, slot = b >> 3;
  const int g    = xcd*8 + (slot >> 2);   // group 0..63 (4 members share an XCD)
  const int j    = slot & 3;              // member: out-col quarter [128j,128j+128)
  const int gb0  = g * ROWS;
  const int pm0 = (j==0)?1:0, pm1 = (j<2)?2:1, pm2 = (j<3)?3:2;  // peers

  // LDS B-frag bases (XOR swizzle col^(batch*8); verified convention from r4)
  const int hbase1 = fm*WIDTH + ((fk*8) ^ (fm*8));
  const int xbase0 = fm*K0    + ((fk*8) ^ (fm*8));
  const int chi    = j*128 + wave*16 + fk*4;   // this lane's 4 out-cols (abs)

  // biases for own out-cols
  const f32x4 b1q = *(const f32x4*)&b1g[chi];
  const f32x4 b2q = *(const f32x4*)&b2g[chi];

  // ---- resident weights: W1/W2 quarter -> VGPRs (128 regs) ----
  bf16x8 w1f[16], w2f[16];
  {
    const bf16* p1 = w1g + (size_t)(j*128 + wave*16 + fm)*WIDTH + fk*8;
    const bf16* p2 = w2g + (size_t)(j*128 + wave*16 + fm)*WIDTH + fk*8;
    #pragma unroll
    for (int kk=0; kk<16; kk++) w1f[kk] = *(const bf16x8*)(p1 + kk*32);
    #pragma unroll
    for (int kk=0; kk<16; kk++) w2f[kk] = *(const bf16x8*)(p2 + kk*32);
  }
  // ---- W0 quarter + W3 full -> LDS, pre-swizzled to fragment order ----
  {
    const bf16* s0 = w0g + (size_t)(j*128 + wave*16 + fm)*K0 + fk*8;
    #pragma unroll
    for (int k=0; k<4; k++){
      bf16x8 v = *(const bf16x8*)(s0 + k*32);
      *(bf16x8*)&w0s[(wave*4+k)*512 + lane*8] = v;
    }
    #pragma unroll
    for (int nt=0; nt<2; nt++)
      #pragma unroll
      for (int kk=0; kk<2; kk++){
        bf16x8 v = *(const bf16x8*)(w3g + (size_t)(nt*16+fm)*WIDTH + wave*64 + kk*32 + fk*8);
        *(bf16x8*)&w3s[(wave*4+nt*2+kk)*512 + lane*8] = v;
      }
  }

  // update-phase constants
  const int urow = t >> 5, ucol = t & 31;
  const float b3v = b3g[ucol];
  float* const outp = out + (size_t)(gb0 + urow)*OUTS + ucol;
  const int arow = (t >> 3) & 15, acol = t & 7;
  const float* const actp = actions + (size_t)(gb0 + arow)*(NSTEPS*ACTD) + acol;
  const int swU    = (urow & 15) << 3;
  const int xin_yh = urow*K0 + (ucol ^ swU);
  const int xin_yl = urow*K0 + ((ucol + 32) ^ swU);
  const int xin_ac = arow*K0 + ((64 + acol) ^ ((arow & 15) << 3));

  // ---- init state ----
  {
    if (t == 0) sdead = 0;
    #pragma unroll
    for (int q=0; q<(ROWS*K0)/512; q++) xin[q*512 + t] = (bf16)0.0f;
    __syncthreads();
    float yv = init_obs[(gb0 + urow)*OBS + ucol];
    yS[urow][ucol] = yv;
    if (j == 0) outp[0] = yv;
    bf16 yh = (bf16)yv;
    xin[xin_yh] = yh;
    xin[xin_yl] = (bf16)(yv - (float)yh);
    if (t < 128) xin[xin_ac] = (bf16)actp[0];
    if (t < 16)  xin[t*K0 + (72 ^ ((t&15)*8))] = (bf16)1.0f;
  }
  __syncthreads();

  #define STORE_OWN(ACC, BQ, HF, HOP) do{ \
    float r0_ = leaky((ACC)[0] + (BQ)[0]); \
    float r1_ = leaky((ACC)[1] + (BQ)[1]); \
    float r2_ = leaky((ACC)[2] + (BQ)[2]); \
    float r3_ = leaky((ACC)[3] + (BQ)[3]); \
    u32x2 pw_ = { pk2(r0_, r1_), pk2(r2_, r3_) }; \
    *(u32x2*)&HF[fm*WIDTH + (chi ^ (fm*8))] = pw_; \
    *(u32x2*)(mbb + ((size_t)((g*3+(HOP))*4 + j))*2048 + fm*128 + wave*16 + fk*4) = pw_; \
  }while(0)

  #define SYNC_HOP(HOP, ST1) do{ \
    __syncthreads(); \
    if (t == 0) __hip_atomic_store(flags + ((g*3+(HOP))*4 + j)*16, (ST1), \
                                   __ATOMIC_RELEASE, __HIP_MEMORY_SCOPE_AGENT); \
    if (wave == 0 && lane < 3){ \
      int pm_ = (lane==0)?pm0:((lane==1)?pm1:pm2); \
      int* fp_ = flags + ((g*3+(HOP))*4 + pm_)*16; \
      int cnt_ = 0; \
      while (!*(volatile int*)&sdead && \
             __hip_atomic_load(fp_, __ATOMIC_ACQUIRE, __HIP_MEMORY_SCOPE_AGENT) < (ST1)){ \
        if (++cnt_ > (1<<21)) { *(volatile int*)&sdead = 1; break; } \
      } \
    } \
    LBAR(); \
  }while(0)

  #define GATHER(HOP, DST) do{ \
    int br_ = t >> 5, cg_ = t & 31; \
    const bf16* s0_ = mbb + ((size_t)((g*3+(HOP))*4 + pm0))*2048 + br_*128 + cg_*4; \
    const bf16* s1_ = mbb + ((size_t)((g*3+(HOP))*4 + pm1))*2048 + br_*128 + cg_*4; \
    const bf16* s2_ = mbb + ((size_t)((g*3+(HOP))*4 + pm2))*2048 + br_*128 + cg_*4; \
    u32x2 v0_ = *(const u32x2*)s0_; \
    u32x2 v1_ = *(const u32x2*)s1_; \
    u32x2 v2_ = *(const u32x2*)s2_; \
    *(u32x2*)&DST[br_*WIDTH + ((pm0*128 + cg_*4) ^ (br_*8))] = v0_; \
    *(u32x2*)&DST[br_*WIDTH + ((pm1*128 + cg_*4) ^ (br_*8))] = v1_; \
    *(u32x2*)&DST[br_*WIDTH + ((pm2*128 + cg_*4) ^ (br_*8))] = v2_; \
    LBAR(); \
  }while(0)

  for (int s=0; s<NSTEPS; ++s){
    const int st1 = s + 1;
    const int sidx = (st1 < NSTEPS) ? st1 : 0;
    float av = actp[(size_t)sidx*ACTD];    // next-step action prefetch

    // ---- l0: xin @ W0q^T (weights LDS, pre-swizzled) ----
    {
      f32x4 acc = {0,0,0,0};
      #pragma unroll
      for (int k=0; k<4; k++){
        bf16x8 a  = *(const bf16x8*)&w0s[(wave*4+k)*512 + lane*8];
        bf16x8 bb = *(const bf16x8*)&xin[xbase0 ^ (k*32)];
        acc = MFMA_B16(a, bb, acc);
      }
      const f32x4 z4 = {0,0,0,0};
      STORE_OWN(acc, z4, hF0, 0);
    }
    SYNC_HOP(0, st1);
    GATHER(0, hF0);

    // ---- l1: hF0 @ W1q^T (weights in VGPRs) ----
    {
      f32x4 acc = {0,0,0,0};
      #pragma unroll
      for (int kk=0; kk<16; kk++){
        bf16x8 bb = *(const bf16x8*)&hF0[hbase1 ^ (kk*32)];
        acc = MFMA_B16(w1f[kk], bb, acc);
      }
      STORE_OWN(acc, b1q, hF1, 1);
    }
    SYNC_HOP(1, st1);
    GATHER(1, hF1);

    // ---- l2: hF1 @ W2q^T ----
    {
      f32x4 acc = {0,0,0,0};
      #pragma unroll
      for (int kk=0; kk<16; kk++){
        bf16x8 bb = *(const bf16x8*)&hF1[hbase1 ^ (kk*32)];
        acc = MFMA_B16(w2f[kk], bb, acc);
      }
      STORE_OWN(acc, b2q, hF0, 2);
    }
    SYNC_HOP(2, st1);
    GATHER(2, hF0);

    // ---- l3 (redundant in all members): K split 8 ways across waves ----
    {
      f32x4 a30 = {0,0,0,0}, a31 = {0,0,0,0};
      #pragma unroll
      for (int kk=0; kk<2; kk++){
        int e = fm*WIDTH + ((wave*64 + kk*32 + fk*8) ^ (fm*8));
        bf16x8 bb = *(const bf16x8*)&hF0[e];
        bf16x8 a0 = *(const bf16x8*)&w3s[(wave*4 + kk)*512 + lane*8];
        bf16x8 a1 = *(const bf16x8*)&w3s[(wave*4 + 2 + kk)*512 + lane*8];
        a30 = MFMA_B16(a0, bb, a30);
        a31 = MFMA_B16(a1, bb, a31);
      }
      *(f32x4*)&pr[wave][fm][fk*4]      = a30;
      *(f32x4*)&pr[wave][fm][16 + fk*4] = a31;
    }
    LBAR();

    // ---- update (redundant, bitwise identical in all members) ----
    {
      float dy = b3v;
      #pragma unroll
      for (int w=0; w<8; w++) dy += pr[w][urow][ucol];
      float yn = yS[urow][ucol] + tauf * dy;
      yS[urow][ucol] = yn;
      if (j == 0) outp[(size_t)st1*OBS] = yn;
      bf16 yh = (bf16)yn;
      xin[xin_yh] = yh;
      xin[xin_yl] = (bf16)(yn - (float)yh);
      if (t < 128) xin[xin_ac] = (bf16)av;
    }
    LBAR();
  }
  asm volatile("s_waitcnt vmcnt(0) lgkmcnt(0)" ::: "memory");
}

extern "C" void kernel_launch(void* const* d_in, const int* in_sizes, int n_in,
                              void* d_out, int out_size, void* d_ws, size_t ws_size,
                              hipStream_t stream){
  const float* init_obs = (const float*)d_in[0];
  const float* actions  = (const float*)d_in[1];
  const float* W0 = (const float*)d_in[2];
  const float* b0 = (const float*)d_in[3];
  const float* W1 = (const float*)d_in[4];
  const float* b1 = (const float*)d_in[5];
  const float* W2 = (const float*)d_in[6];
  const float* b2 = (const float*)d_in[7];
  const float* W3 = (const float*)d_in[8];
  const float* b3 = (const float*)d_in[9];
  const int*  tau = (const int*)d_in[10];
  bf16* wsb = (bf16*)d_ws;
  float* out = (float*)d_out;

  hipLaunchKernelGGL(setup_kernel, dim3(512), dim3(256), 0, stream,
                     W0, b0, W1, W2, W3, tau, wsb);
  hipLaunchKernelGGL(ode_kernel, dim3(256), dim3(512), 0, stream,
                     init_obs, actions, b1, b2, b3, wsb, out);
}

// Round 7
// 5878.730 us; speedup vs baseline: 7.8987x; 5.1853x over previous
//
#include <hip/hip_runtime.h>
#include <hip/hip_bf16.h>
#include <stdint.h>

typedef __bf16 bf16;
typedef __attribute__((ext_vector_type(8))) __bf16 bf16x8;
typedef __attribute__((ext_vector_type(4))) float f32x4;
typedef __attribute__((ext_vector_type(2))) unsigned int u32x2;

#define MFMA_B16(a,b,c) __builtin_amdgcn_mfma_f32_16x16x32_bf16((a),(b),(c),0,0,0)

// problem dims
#define BATCH  1024
#define NSTEPS 1024
#define OBS    32
#define ACTD   8
#define WIDTH  512
#define ROWS   16
#define OUTS   ((NSTEPS+1)*OBS)
#define K0     128   // [y_hi 32 | y_lo 32 | act 8 | one@72 | pad -> 128]

// ws layout (bf16 element offsets)
#define W0P_OFF 0
#define W0P_N   (WIDTH*K0)          // 65536
#define W1_OFF  (W0P_OFF + W0P_N)
#define WBIG_N  (WIDTH*WIDTH)       // 262144
#define W2_OFF  (W1_OFF + WBIG_N)
#define W3_OFF  (W2_OFF + WBIG_N)
#define W3_N    (OBS*WIDTH)         // 16384
#define TAU_OFF (W3_OFF + W3_N)
// mailboxes: 64 groups x 3 hops x 4 members x 4KB
#define MB_OFF  606720
#define MB_N    (64*3*4*2048)
#define FLAG_DW_IDX (((MB_OFF + MB_N)/2) + 64)
#define NFLAG   (64*3*4*16)

#define LBAR() do{ asm volatile("s_waitcnt lgkmcnt(0)" ::: "memory"); \
                   __builtin_amdgcn_s_barrier(); \
                   __builtin_amdgcn_sched_barrier(0); }while(0)
#define FBAR() do{ asm volatile("s_waitcnt vmcnt(0) lgkmcnt(0)" ::: "memory"); \
                   __builtin_amdgcn_s_barrier(); \
                   __builtin_amdgcn_sched_barrier(0); }while(0)

__global__ void setup_kernel(const float* __restrict__ W0, const float* __restrict__ b0r,
                             const float* __restrict__ W1, const float* __restrict__ W2,
                             const float* __restrict__ W3,
                             const int* __restrict__ tau, bf16* __restrict__ wsb){
  int i = blockIdx.x*blockDim.x + threadIdx.x;
  int stride = gridDim.x*blockDim.x;
  for (int idx=i; idx<W0P_N; idx+=stride){
    int r = idx >> 7, c = idx & 127;
    float v = 0.0f;
    if (c < 32)       v = W0[r*40 + c];
    else if (c < 64)  v = W0[r*40 + (c-32)];
    else if (c < 72)  v = W0[r*40 + 32 + (c-64)];
    else if (c == 72) v = b0r[r];
    wsb[W0P_OFF+idx] = (bf16)v;
  }
  for (int idx=i; idx<WBIG_N; idx+=stride) wsb[W1_OFF+idx] = (bf16)W1[idx];
  for (int idx=i; idx<WBIG_N; idx+=stride) wsb[W2_OFF+idx] = (bf16)W2[idx];
  for (int idx=i; idx<W3_N;  idx+=stride) wsb[W3_OFF+idx] = (bf16)W3[idx];
  int* flags = ((int*)wsb) + FLAG_DW_IDX;
  for (int idx=i; idx<NFLAG; idx+=stride) flags[idx] = 0;
  if (i==0){
    int ti = *tau;
    float tf;
    if (ti >= -1000000 && ti <= 1000000) tf = (float)ti;
    else { union {int q; float f;} u; u.q = ti; tf = u.f; }
    *(float*)(wsb + TAU_OFF) = tf;
  }
}

__device__ __forceinline__ float leaky(float v){ return v < 0.0f ? 0.01f*v : v; }

__device__ __forceinline__ uint32_t pk2(float a, float b){
  union { bf16 h; uint16_t u; } ua, ub; ua.h = (bf16)a; ub.h = (bf16)b;
  return (uint32_t)ua.u | ((uint32_t)ub.u << 16);
}

__global__ __launch_bounds__(512, 2)
void ode_kernel(const float* __restrict__ init_obs, const float* __restrict__ actions,
                const float* __restrict__ b1g, const float* __restrict__ b2g,
                const float* __restrict__ b3g,
                bf16* __restrict__ wsrw, float* __restrict__ out){
  const bf16* w0g = wsrw + W0P_OFF;
  const bf16* w1g = wsrw + W1_OFF;
  const bf16* w2g = wsrw + W2_OFF;
  const bf16* w3g = wsrw + W3_OFF;
  unsigned long long* mbq = (unsigned long long*)(wsrw + MB_OFF);
  float* mbf = (float*)(wsrw + MB_OFF);
  int* flags = ((int*)wsrw) + FLAG_DW_IDX;
  const float tauf = *(const float*)(wsrw + TAU_OFF);

  __shared__ alignas(16) bf16 w0s[32*512];     // 32KB pre-swizzled W0 quarter
  __shared__ alignas(16) bf16 w3s[8*512];      // 8KB  pre-swizzled W3 own-K slice
  __shared__ alignas(16) bf16 hF0[ROWS*WIDTH]; // 16KB
  __shared__ alignas(16) bf16 hF1[ROWS*WIDTH]; // 16KB
  __shared__ alignas(16) bf16 xin[ROWS*K0];    // 4KB
  __shared__ alignas(16) float pr[8][16][20];  // 10KB l3 partials
  __shared__ float yS[ROWS][OBS];              // 2KB
  __shared__ int sdead;

  const int t    = threadIdx.x;
  const int lane = t & 63;
  const int wave = t >> 6;
  const int fm   = lane & 15;
  const int fk   = lane >> 4;
  const int b    = blockIdx.x;
  const int xcd  = b & 7, slot = b >> 3;
  const int g    = xcd*8 + (slot >> 2);   // group 0..63 (members adjacent-XCD)
  const int j    = slot & 3;              // member: out-col quarter
  const int gb0  = g * ROWS;
  const int pm0 = (j==0)?1:0, pm1 = (j<2)?2:1, pm2 = (j<3)?3:2;

  const int hbase1 = fm*WIDTH + ((fk*8) ^ (fm*8));
  const int xbase0 = fm*K0    + ((fk*8) ^ (fm*8));
  const int chi    = j*128 + wave*16 + fk*4;

  const f32x4 b1q = *(const f32x4*)&b1g[chi];
  const f32x4 b2q = *(const f32x4*)&b2g[chi];

  // ---- resident weights: W1/W2 quarter -> VGPRs (128 regs), pinned ----
  bf16x8 w1f[16], w2f[16];
  {
    const bf16* p1 = w1g + (size_t)(j*128 + wave*16 + fm)*WIDTH + fk*8;
    const bf16* p2 = w2g + (size_t)(j*128 + wave*16 + fm)*WIDTH + fk*8;
    #pragma unroll
    for (int kk=0; kk<16; kk++) w1f[kk] = *(const bf16x8*)(p1 + kk*32);
    #pragma unroll
    for (int kk=0; kk<16; kk++) w2f[kk] = *(const bf16x8*)(p2 + kk*32);
  }
  // ---- W0 quarter + own W3 K-slice -> LDS, fragment order ----
  {
    const bf16* s0 = w0g + (size_t)(j*128 + wave*16 + fm)*K0 + fk*8;
    #pragma unroll
    for (int k=0; k<4; k++){
      bf16x8 v = *(const bf16x8*)(s0 + k*32);
      *(bf16x8*)&w0s[(wave*4+k)*512 + lane*8] = v;
    }
    const int nt_ = wave & 1, q_ = wave >> 1;
    bf16x8 v3 = *(const bf16x8*)(w3g + (size_t)(nt_*16 + fm)*WIDTH + j*128 + q_*32 + fk*8);
    *(bf16x8*)&w3s[wave*512 + lane*8] = v3;
  }

  // update-phase constants
  const int urow = t >> 5, ucol = t & 31;
  const float b3v = b3g[ucol];
  float* const outp = out + (size_t)(gb0 + urow)*OUTS + ucol;
  const int arow = (t >> 3) & 15, acol = t & 7;
  const float* const actp = actions + (size_t)(gb0 + arow)*(NSTEPS*ACTD) + acol;
  const int swU    = (urow & 15) << 3;
  const int xin_yh = urow*K0 + (ucol ^ swU);
  const int xin_yl = urow*K0 + ((ucol + 32) ^ swU);
  const int xin_ac = arow*K0 + ((64 + acol) ^ ((arow & 15) << 3));

  // ---- init state ----
  {
    if (t == 0) sdead = 0;
    #pragma unroll
    for (int q=0; q<(ROWS*K0)/512; q++) xin[q*512 + t] = (bf16)0.0f;
    __syncthreads();
    float yv = init_obs[(gb0 + urow)*OBS + ucol];
    yS[urow][ucol] = yv;
    if (j == 0) outp[0] = yv;
    bf16 yh = (bf16)yv;
    xin[xin_yh] = yh;
    xin[xin_yl] = (bf16)(yv - (float)yh);
    if (t < 128) xin[xin_ac] = (bf16)actp[0];
    if (t < 16)  xin[t*K0 + (72 ^ ((t&15)*8))] = (bf16)1.0f;
  }
  __syncthreads();

  // pin resident weights (prevents remat/spill-to-stream: r5's VGPR=120 bug)
  #pragma unroll
  for (int kk=0; kk<16; kk++){ asm volatile("" : "+v"(w1f[kk])); }
  #pragma unroll
  for (int kk=0; kk<16; kk++){ asm volatile("" : "+v"(w2f[kk])); }

  #define STORE_OWN01(ACC, BQ, HF, HOP) do{ \
    float r0_ = leaky((ACC)[0] + (BQ)[0]); \
    float r1_ = leaky((ACC)[1] + (BQ)[1]); \
    float r2_ = leaky((ACC)[2] + (BQ)[2]); \
    float r3_ = leaky((ACC)[3] + (BQ)[3]); \
    union { u32x2 v; unsigned long long q; } pu_; \
    pu_.v = (u32x2){ pk2(r0_, r1_), pk2(r2_, r3_) }; \
    *(u32x2*)&HF[fm*WIDTH + (chi ^ (fm*8))] = pu_.v; \
    __hip_atomic_store(mbq + (size_t)((g*3+(HOP))*4 + j)*512 + fm*32 + wave*4 + fk, \
                       pu_.q, __ATOMIC_RELAXED, __HIP_MEMORY_SCOPE_AGENT); \
  }while(0)

  // relaxed flag protocol: FBAR drains vmcnt (mailbox committed), flag store,
  // 3 lanes poll peers (relaxed, no cache-wide inv), barrier releases the WG.
  #define SYNC_HOP(HOP, ST1) do{ \
    FBAR(); \
    if (t == 0) __hip_atomic_store(flags + ((g*3+(HOP))*4 + j)*16, (ST1), \
                                   __ATOMIC_RELAXED, __HIP_MEMORY_SCOPE_AGENT); \
    if (wave == 0 && lane < 3){ \
      int pm_ = (lane==0)?pm0:((lane==1)?pm1:pm2); \
      const int* fp_ = flags + ((g*3+(HOP))*4 + pm_)*16; \
      int cnt_ = 0; \
      while (!*(volatile int*)&sdead && \
             __hip_atomic_load(fp_, __ATOMIC_RELAXED, __HIP_MEMORY_SCOPE_AGENT) < (ST1)){ \
        __builtin_amdgcn_s_sleep(1); \
        if (++cnt_ > (1<<20)) { *(volatile int*)&sdead = 1; break; } \
      } \
    } \
    LBAR(); \
  }while(0)

  #define GATHER01(HOP, DST) do{ \
    const int br_ = t >> 5, cg_ = t & 31; \
    const size_t hb_ = (size_t)((g*3+(HOP))*4); \
    unsigned long long v0_ = __hip_atomic_load(mbq + (hb_+pm0)*512 + br_*32 + cg_, \
                                 __ATOMIC_RELAXED, __HIP_MEMORY_SCOPE_AGENT); \
    unsigned long long v1_ = __hip_atomic_load(mbq + (hb_+pm1)*512 + br_*32 + cg_, \
                                 __ATOMIC_RELAXED, __HIP_MEMORY_SCOPE_AGENT); \
    unsigned long long v2_ = __hip_atomic_load(mbq + (hb_+pm2)*512 + br_*32 + cg_, \
                                 __ATOMIC_RELAXED, __HIP_MEMORY_SCOPE_AGENT); \
    *(unsigned long long*)&DST[br_*WIDTH + ((pm0*128 + cg_*4) ^ (br_*8))] = v0_; \
    *(unsigned long long*)&DST[br_*WIDTH + ((pm1*128 + cg_*4) ^ (br_*8))] = v1_; \
    *(unsigned long long*)&DST[br_*WIDTH + ((pm2*128 + cg_*4) ^ (br_*8))] = v2_; \
    LBAR(); \
  }while(0)

  const f32x4 z4 = {0,0,0,0};

  for (int s=0; s<NSTEPS; ++s){
    const int st1 = s + 1;
    const int sidx = (st1 < NSTEPS) ? st1 : 0;
    float av = actp[(size_t)sidx*ACTD];

    // ---- l0: xin @ W0q^T ----
    {
      f32x4 acc = {0,0,0,0};
      #pragma unroll
      for (int k=0; k<4; k++){
        bf16x8 a  = *(const bf16x8*)&w0s[(wave*4+k)*512 + lane*8];
        bf16x8 bb = *(const bf16x8*)&xin[xbase0 ^ (k*32)];
        acc = MFMA_B16(a, bb, acc);
      }
      STORE_OWN01(acc, z4, hF0, 0);
    }
    SYNC_HOP(0, st1);
    GATHER01(0, hF0);

    // ---- l1: hF0 @ W1q^T (resident VGPR weights) ----
    {
      f32x4 acc = {0,0,0,0};
      #pragma unroll
      for (int kk=0; kk<16; kk++){
        bf16x8 bb = *(const bf16x8*)&hF0[hbase1 ^ (kk*32)];
        acc = MFMA_B16(w1f[kk], bb, acc);
      }
      STORE_OWN01(acc, b1q, hF1, 1);
    }
    SYNC_HOP(1, st1);
    GATHER01(1, hF1);

    // ---- l2: hF1 @ W2q^T -> own slice to LDS only (l3 needs only own cols) ----
    {
      f32x4 acc = {0,0,0,0};
      #pragma unroll
      for (int kk=0; kk<16; kk++){
        bf16x8 bb = *(const bf16x8*)&hF1[hbase1 ^ (kk*32)];
        acc = MFMA_B16(w2f[kk], bb, acc);
      }
      u32x2 pw = { pk2(leaky(acc[0]+b2q[0]), leaky(acc[1]+b2q[1])),
                   pk2(leaky(acc[2]+b2q[2]), leaky(acc[3]+b2q[3])) };
      *(u32x2*)&hF0[fm*WIDTH + (chi ^ (fm*8))] = pw;
    }
    LBAR();

    // ---- l3 partial over own 128 K-cols (8 waves: 2 n-tiles x 4 K-chunks) ----
    {
      const int q_ = wave >> 1;
      bf16x8 a  = *(const bf16x8*)&w3s[wave*512 + lane*8];
      bf16x8 bb = *(const bf16x8*)&hF0[fm*WIDTH + ((j*128 + q_*32 + fk*8) ^ (fm*8))];
      f32x4 a3 = MFMA_B16(a, bb, z4);
      *(f32x4*)&pr[wave][fm][fk*4] = a3;
    }
    LBAR();

    // ---- reduce own partials -> mailbox (fp32, 2KB) ----
    float ownv;
    {
      const int ntc = ucol >> 4, c15 = ucol & 15;
      ownv = ((pr[ntc][urow][c15] + pr[2+ntc][urow][c15])
              + pr[4+ntc][urow][c15]) + pr[6+ntc][urow][c15];
      __hip_atomic_store(mbf + (size_t)((g*3+2)*4 + j)*1024 + urow*32 + ucol,
                         ownv, __ATOMIC_RELAXED, __HIP_MEMORY_SCOPE_AGENT);
    }
    SYNC_HOP(2, st1);

    // ---- update: fixed-order member sum -> Euler -> emit -> reseed ----
    {
      float vals[4];
      #pragma unroll
      for (int m=0; m<4; m++){
        if (m == j) vals[m] = ownv;
        else vals[m] = __hip_atomic_load(mbf + (size_t)((g*3+2)*4 + m)*1024 + urow*32 + ucol,
                                         __ATOMIC_RELAXED, __HIP_MEMORY_SCOPE_AGENT);
      }
      float dy = b3v + vals[0] + vals[1] + vals[2] + vals[3];
      float yn = yS[urow][ucol] + tauf * dy;
      yS[urow][ucol] = yn;
      if (j == 0) outp[(size_t)st1*OBS] = yn;
      bf16 yh = (bf16)yn;
      xin[xin_yh] = yh;
      xin[xin_yl] = (bf16)(yn - (float)yh);
      if (t < 128) xin[xin_ac] = (bf16)av;
    }
    LBAR();
  }
  asm volatile("s_waitcnt vmcnt(0) lgkmcnt(0)" ::: "memory");
}

extern "C" void kernel_launch(void* const* d_in, const int* in_sizes, int n_in,
                              void* d_out, int out_size, void* d_ws, size_t ws_size,
                              hipStream_t stream){
  const float* init_obs = (const float*)d_in[0];
  const float* actions  = (const float*)d_in[1];
  const float* W0 = (const float*)d_in[2];
  const float* b0 = (const float*)d_in[3];
  const float* W1 = (const float*)d_in[4];
  const float* b1 = (const float*)d_in[5];
  const float* W2 = (const float*)d_in[6];
  const float* b2 = (const float*)d_in[7];
  const float* W3 = (const float*)d_in[8];
  const float* b3 = (const float*)d_in[9];
  const int*  tau = (const int*)d_in[10];
  bf16* wsb = (bf16*)d_ws;
  float* out = (float*)d_out;

  hipLaunchKernelGGL(setup_kernel, dim3(512), dim3(256), 0, stream,
                     W0, b0, W1, W2, W3, tau, wsb);
  hipLaunchKernelGGL(ode_kernel, dim3(256), dim3(512), 0, stream,
                     init_obs, actions, b1, b2, b3, wsb, out);
}

// Round 8
// 4629.401 us; speedup vs baseline: 10.0303x; 1.2699x over previous
//
#include <hip/hip_runtime.h>
#include <hip/hip_bf16.h>
#include <stdint.h>

typedef __bf16 bf16;
typedef __attribute__((ext_vector_type(8))) __bf16 bf16x8;
typedef __attribute__((ext_vector_type(4))) float f32x4;
typedef __attribute__((ext_vector_type(2))) unsigned int u32x2;

#define MFMA_B16(a,b,c) __builtin_amdgcn_mfma_f32_16x16x32_bf16((a),(b),(c),0,0,0)

// problem dims
#define BATCH  1024
#define NSTEPS 1024
#define OBS    32
#define ACTD   8
#define WIDTH  512
#define ROWS   16
#define OUTS   ((NSTEPS+1)*OBS)
#define K0     128   // [y_hi 32 | y_lo 32 | act 8 | one@72 | zero-pad -> 128]

// ws layout (bf16 element offsets)
#define W0P_OFF 0
#define W0P_N   (WIDTH*K0)          // 65536
#define W1_OFF  (W0P_OFF + W0P_N)
#define WBIG_N  (WIDTH*WIDTH)       // 262144
#define W2_OFF  (W1_OFF + WBIG_N)
#define W3_OFF  (W2_OFF + WBIG_N)
#define W3_N    (OBS*WIDTH)         // 16384
#define TAU_OFF (W3_OFF + W3_N)
// mailboxes: 64 groups x 3 hop-slots x 4 members x 4KB (slot1 unused now)
#define MB_OFF  606720
#define MB_N    (64*3*4*2048)
#define FLAG_DW_IDX (((MB_OFF + MB_N)/2) + 64)
#define NFLAG   (64*3*4*16)

#define LBAR() do{ asm volatile("s_waitcnt lgkmcnt(0)" ::: "memory"); \
                   __builtin_amdgcn_s_barrier(); \
                   __builtin_amdgcn_sched_barrier(0); }while(0)
#define FBAR() do{ asm volatile("s_waitcnt vmcnt(0) lgkmcnt(0)" ::: "memory"); \
                   __builtin_amdgcn_s_barrier(); \
                   __builtin_amdgcn_sched_barrier(0); }while(0)

__global__ void setup_kernel(const float* __restrict__ W0, const float* __restrict__ b0r,
                             const float* __restrict__ W1, const float* __restrict__ W2,
                             const float* __restrict__ W3,
                             const int* __restrict__ tau, bf16* __restrict__ wsb){
  int i = blockIdx.x*blockDim.x + threadIdx.x;
  int stride = gridDim.x*blockDim.x;
  for (int idx=i; idx<W0P_N; idx+=stride){
    int r = idx >> 7, c = idx & 127;
    float v = 0.0f;
    if (c < 32)       v = W0[r*40 + c];
    else if (c < 64)  v = W0[r*40 + (c-32)];
    else if (c < 72)  v = W0[r*40 + 32 + (c-64)];
    else if (c == 72) v = b0r[r];
    wsb[W0P_OFF+idx] = (bf16)v;
  }
  for (int idx=i; idx<WBIG_N; idx+=stride) wsb[W1_OFF+idx] = (bf16)W1[idx];
  for (int idx=i; idx<WBIG_N; idx+=stride) wsb[W2_OFF+idx] = (bf16)W2[idx];
  for (int idx=i; idx<W3_N;  idx+=stride) wsb[W3_OFF+idx] = (bf16)W3[idx];
  int* flags = ((int*)wsb) + FLAG_DW_IDX;
  for (int idx=i; idx<NFLAG; idx+=stride) flags[idx] = 0;
  if (i==0){
    int ti = *tau;
    float tf;
    if (ti >= -1000000 && ti <= 1000000) tf = (float)ti;
    else { union {int q; float f;} u; u.q = ti; tf = u.f; }
    *(float*)(wsb + TAU_OFF) = tf;
  }
}

__device__ __forceinline__ float leaky(float v){ return v < 0.0f ? 0.01f*v : v; }

__device__ __forceinline__ uint32_t pk2(float a, float b){
  union { bf16 h; uint16_t u; } ua, ub; ua.h = (bf16)a; ub.h = (bf16)b;
  return (uint32_t)ua.u | ((uint32_t)ub.u << 16);
}

__global__ __launch_bounds__(512, 2)
void ode_kernel(const float* __restrict__ init_obs, const float* __restrict__ actions,
                const float* __restrict__ b1g, const float* __restrict__ b2g,
                const float* __restrict__ b3g,
                bf16* __restrict__ wsrw, float* __restrict__ out){
  const bf16* w0g = wsrw + W0P_OFF;
  const bf16* w1g = wsrw + W1_OFF;
  const bf16* w2g = wsrw + W2_OFF;
  const bf16* w3g = wsrw + W3_OFF;
  unsigned long long* mbq = (unsigned long long*)(wsrw + MB_OFF);
  float* mbf = (float*)(wsrw + MB_OFF);
  int* flags = ((int*)wsrw) + FLAG_DW_IDX;
  const float tauf = *(const float*)(wsrw + TAU_OFF);

  __shared__ alignas(16) bf16 w0s[96*512];     // 96KB full W0, fragment order (3 k-steps)
  __shared__ alignas(16) bf16 w3s[8*512];      // 8KB  W3 own-K slice, fragment order
  __shared__ alignas(16) bf16 hF0[ROWS*WIDTH]; // 16KB h0 (full, local) / h2 own cols
  __shared__ alignas(16) bf16 hF1[ROWS*WIDTH]; // 16KB h1 (own + gathered)
  __shared__ alignas(16) bf16 xin[ROWS*K0];    // 4KB
  __shared__ alignas(16) float pr[8][16][20];  // 10KB l3 partials
  __shared__ float yS[ROWS][OBS];              // 2KB
  __shared__ int sdead;

  const int t    = threadIdx.x;
  const int lane = t & 63;
  const int wave = t >> 6;
  const int fm   = lane & 15;
  const int fk   = lane >> 4;
  const int b    = blockIdx.x;
  const int xcd  = b & 7, slot = b >> 3;
  const int g    = xcd*8 + (slot >> 2);   // group 0..63 (members share an XCD)
  const int j    = slot & 3;              // member: out-col quarter
  const int gb0  = g * ROWS;
  const int pm0 = (j==0)?1:0, pm1 = (j<2)?2:1, pm2 = (j<3)?3:2;

  const int hbase1 = fm*WIDTH + ((fk*8) ^ (fm*8));
  const int xbase0 = fm*K0    + ((fk*8) ^ (fm*8));
  const int chi    = j*128 + wave*16 + fk*4;

  const f32x4 b1q = *(const f32x4*)&b1g[chi];
  const f32x4 b2q = *(const f32x4*)&b2g[chi];

  // ---- resident weights: W1/W2 quarter -> VGPRs (128 regs), pinned ----
  bf16x8 w1f[16], w2f[16];
  {
    const bf16* p1 = w1g + (size_t)(j*128 + wave*16 + fm)*WIDTH + fk*8;
    const bf16* p2 = w2g + (size_t)(j*128 + wave*16 + fm)*WIDTH + fk*8;
    #pragma unroll
    for (int kk=0; kk<16; kk++) w1f[kk] = *(const bf16x8*)(p1 + kk*32);
    #pragma unroll
    for (int kk=0; kk<16; kk++) w2f[kk] = *(const bf16x8*)(p2 + kk*32);
  }
  // ---- FULL W0 (3 k-steps) + own W3 K-slice -> LDS, fragment order ----
  {
    #pragma unroll
    for (int n=0; n<4; n++){
      const bf16* s0 = w0g + (size_t)((wave*4+n)*16 + fm)*K0 + fk*8;
      #pragma unroll
      for (int k=0; k<3; k++){
        bf16x8 v = *(const bf16x8*)(s0 + k*32);
        *(bf16x8*)&w0s[((wave*4+n)*3 + k)*512 + lane*8] = v;
      }
    }
    const int nt_ = wave & 1, q_ = wave >> 1;
    bf16x8 v3 = *(const bf16x8*)(w3g + (size_t)(nt_*16 + fm)*WIDTH + j*128 + q_*32 + fk*8);
    *(bf16x8*)&w3s[wave*512 + lane*8] = v3;
  }

  // update-phase constants
  const int urow = t >> 5, ucol = t & 31;
  const float b3v = b3g[ucol];
  float* const outp = out + (size_t)(gb0 + urow)*OUTS + ucol;
  const int arow = (t >> 3) & 15, acol = t & 7;
  const float* const actp = actions + (size_t)(gb0 + arow)*(NSTEPS*ACTD) + acol;
  const int swU    = (urow & 15) << 3;
  const int xin_yh = urow*K0 + (ucol ^ swU);
  const int xin_yl = urow*K0 + ((ucol + 32) ^ swU);
  const int xin_ac = arow*K0 + ((64 + acol) ^ ((arow & 15) << 3));

  // ---- init state ----
  {
    if (t == 0) sdead = 0;
    #pragma unroll
    for (int q=0; q<(ROWS*K0)/512; q++) xin[q*512 + t] = (bf16)0.0f;
    __syncthreads();
    float yv = init_obs[(gb0 + urow)*OBS + ucol];
    yS[urow][ucol] = yv;
    if (j == 0) outp[0] = yv;
    bf16 yh = (bf16)yv;
    xin[xin_yh] = yh;
    xin[xin_yl] = (bf16)(yv - (float)yh);
    if (t < 128) xin[xin_ac] = (bf16)actp[0];
    if (t < 16)  xin[t*K0 + (72 ^ ((t&15)*8))] = (bf16)1.0f;
  }
  __syncthreads();

  // pin resident weights (prevents remat/spill-to-stream)
  #pragma unroll
  for (int kk=0; kk<16; kk++){ asm volatile("" : "+v"(w1f[kk])); }
  #pragma unroll
  for (int kk=0; kk<16; kk++){ asm volatile("" : "+v"(w2f[kk])); }

  #define STORE_OWN01(ACC, BQ, HF, HOP) do{ \
    float r0_ = leaky((ACC)[0] + (BQ)[0]); \
    float r1_ = leaky((ACC)[1] + (BQ)[1]); \
    float r2_ = leaky((ACC)[2] + (BQ)[2]); \
    float r3_ = leaky((ACC)[3] + (BQ)[3]); \
    union { u32x2 v; unsigned long long q; } pu_; \
    pu_.v = (u32x2){ pk2(r0_, r1_), pk2(r2_, r3_) }; \
    *(u32x2*)&HF[fm*WIDTH + (chi ^ (fm*8))] = pu_.v; \
    __hip_atomic_store(mbq + (size_t)((g*3+(HOP))*4 + j)*512 + fm*32 + wave*4 + fk, \
                       pu_.q, __ATOMIC_RELAXED, __HIP_MEMORY_SCOPE_AGENT); \
  }while(0)

  #define SYNC_HOP(HOP, ST1) do{ \
    FBAR(); \
    if (t == 0) __hip_atomic_store(flags + ((g*3+(HOP))*4 + j)*16, (ST1), \
                                   __ATOMIC_RELAXED, __HIP_MEMORY_SCOPE_AGENT); \
    if (wave == 0 && lane < 3){ \
      int pm_ = (lane==0)?pm0:((lane==1)?pm1:pm2); \
      const int* fp_ = flags + ((g*3+(HOP))*4 + pm_)*16; \
      int cnt_ = 0; \
      while (!*(volatile int*)&sdead && \
             __hip_atomic_load(fp_, __ATOMIC_RELAXED, __HIP_MEMORY_SCOPE_AGENT) < (ST1)){ \
        __builtin_amdgcn_s_sleep(1); \
        if (++cnt_ > (1<<20)) { *(volatile int*)&sdead = 1; break; } \
      } \
    } \
    LBAR(); \
  }while(0)

  #define GATHER01(HOP, DST) do{ \
    const int br_ = t >> 5, cg_ = t & 31; \
    const size_t hb_ = (size_t)((g*3+(HOP))*4); \
    unsigned long long v0_ = __hip_atomic_load(mbq + (hb_+pm0)*512 + br_*32 + cg_, \
                                 __ATOMIC_RELAXED, __HIP_MEMORY_SCOPE_AGENT); \
    unsigned long long v1_ = __hip_atomic_load(mbq + (hb_+pm1)*512 + br_*32 + cg_, \
                                 __ATOMIC_RELAXED, __HIP_MEMORY_SCOPE_AGENT); \
    unsigned long long v2_ = __hip_atomic_load(mbq + (hb_+pm2)*512 + br_*32 + cg_, \
                                 __ATOMIC_RELAXED, __HIP_MEMORY_SCOPE_AGENT); \
    *(unsigned long long*)&DST[br_*WIDTH + ((pm0*128 + cg_*4) ^ (br_*8))] = v0_; \
    *(unsigned long long*)&DST[br_*WIDTH + ((pm1*128 + cg_*4) ^ (br_*8))] = v1_; \
    *(unsigned long long*)&DST[br_*WIDTH + ((pm2*128 + cg_*4) ^ (br_*8))] = v2_; \
    LBAR(); \
  }while(0)

  // l2 quarter (Q literal -> static w2f indices)
  #define L2Q(Q) do{ \
    _Pragma("unroll") \
    for (int kk=(Q)*4; kk<(Q)*4+4; kk++){ \
      bf16x8 bb = *(const bf16x8*)&hF1[hbase1 ^ (kk*32)]; \
      acc2 = MFMA_B16(w2f[kk], bb, acc2); \
    } \
  }while(0)

  // mid-l2 sync: poll peers' h1 flags, gather their slices (overlapped w/ own-Q MFMAs)
  #define L2MID() do{ \
    if (wave == 0 && lane < 3){ \
      int pm_ = (lane==0)?pm0:((lane==1)?pm1:pm2); \
      const int* fp_ = flags + ((g*3+0)*4 + pm_)*16; \
      int cnt_ = 0; \
      while (!*(volatile int*)&sdead && \
             __hip_atomic_load(fp_, __ATOMIC_RELAXED, __HIP_MEMORY_SCOPE_AGENT) < st1){ \
        __builtin_amdgcn_s_sleep(1); \
        if (++cnt_ > (1<<20)) { *(volatile int*)&sdead = 1; break; } \
      } \
    } \
    LBAR(); \
    GATHER01(0, hF1); \
  }while(0)

  const f32x4 z4 = {0,0,0,0};

  for (int s=0; s<NSTEPS; ++s){
    const int st1 = s + 1;
    const int sidx = (st1 < NSTEPS) ? st1 : 0;
    float av = actp[(size_t)sidx*ACTD];

    // ---- l0 (replicated, full 512 cols): xin @ W0^T, local only ----
    {
      #pragma unroll
      for (int n=0; n<4; n++){
        f32x4 acc = {0,0,0,0};
        #pragma unroll
        for (int k=0; k<3; k++){
          bf16x8 a  = *(const bf16x8*)&w0s[((wave*4+n)*3 + k)*512 + lane*8];
          bf16x8 bb = *(const bf16x8*)&xin[xbase0 ^ (k*32)];
          acc = MFMA_B16(a, bb, acc);
        }
        int ob = (wave*4+n)*16 + fk*4;
        u32x2 pw = { pk2(leaky(acc[0]), leaky(acc[1])),
                     pk2(leaky(acc[2]), leaky(acc[3])) };
        *(u32x2*)&hF0[fm*WIDTH + (ob ^ (fm*8))] = pw;
      }
    }
    LBAR();

    // ---- l1: hF0(full h0) @ W1q^T -> own 128 cols, publish (hop 0) ----
    {
      f32x4 acc = {0,0,0,0};
      #pragma unroll
      for (int kk=0; kk<16; kk++){
        bf16x8 bb = *(const bf16x8*)&hF0[hbase1 ^ (kk*32)];
        acc = MFMA_B16(w1f[kk], bb, acc);
      }
      STORE_OWN01(acc, b1q, hF1, 0);
    }
    FBAR();
    if (t == 0) __hip_atomic_store(flags + ((g*3+0)*4 + j)*16, st1,
                                   __ATOMIC_RELAXED, __HIP_MEMORY_SCOPE_AGENT);

    // ---- l2: own-K quarter first (overlaps peers' flag+gather), then rest ----
    f32x4 acc2 = {0,0,0,0};
    switch (j){
      case 0:  L2Q(0); L2MID(); L2Q(1); L2Q(2); L2Q(3); break;
      case 1:  L2Q(1); L2MID(); L2Q(0); L2Q(2); L2Q(3); break;
      case 2:  L2Q(2); L2MID(); L2Q(0); L2Q(1); L2Q(3); break;
      default: L2Q(3); L2MID(); L2Q(0); L2Q(1); L2Q(2); break;
    }
    {
      u32x2 pw = { pk2(leaky(acc2[0]+b2q[0]), leaky(acc2[1]+b2q[1])),
                   pk2(leaky(acc2[2]+b2q[2]), leaky(acc2[3]+b2q[3])) };
      *(u32x2*)&hF0[fm*WIDTH + (chi ^ (fm*8))] = pw;
    }
    LBAR();

    // ---- l3 partial over own 128 K-cols ----
    {
      const int q_ = wave >> 1;
      bf16x8 a  = *(const bf16x8*)&w3s[wave*512 + lane*8];
      bf16x8 bb = *(const bf16x8*)&hF0[fm*WIDTH + ((j*128 + q_*32 + fk*8) ^ (fm*8))];
      f32x4 a3 = MFMA_B16(a, bb, z4);
      *(f32x4*)&pr[wave][fm][fk*4] = a3;
    }
    LBAR();

    // ---- reduce own partials -> mailbox (fp32); reseed action early ----
    float ownv;
    {
      if (t < 128) xin[xin_ac] = (bf16)av;   // independent of dy; hide under hop
      const int ntc = ucol >> 4, c15 = ucol & 15;
      ownv = ((pr[ntc][urow][c15] + pr[2+ntc][urow][c15])
              + pr[4+ntc][urow][c15]) + pr[6+ntc][urow][c15];
      __hip_atomic_store(mbf + (size_t)((g*3+2)*4 + j)*1024 + urow*32 + ucol,
                         ownv, __ATOMIC_RELAXED, __HIP_MEMORY_SCOPE_AGENT);
    }
    SYNC_HOP(2, st1);

    // ---- update: fixed-order member sum -> Euler -> emit -> reseed ----
    {
      float vals[4];
      #pragma unroll
      for (int m=0; m<4; m++){
        if (m == j) vals[m] = ownv;
        else vals[m] = __hip_atomic_load(mbf + (size_t)((g*3+2)*4 + m)*1024 + urow*32 + ucol,
                                         __ATOMIC_RELAXED, __HIP_MEMORY_SCOPE_AGENT);
      }
      float dy = b3v + vals[0] + vals[1] + vals[2] + vals[3];
      float yn = yS[urow][ucol] + tauf * dy;
      yS[urow][ucol] = yn;
      if (j == 0) outp[(size_t)st1*OBS] = yn;
      bf16 yh = (bf16)yn;
      xin[xin_yh] = yh;
      xin[xin_yl] = (bf16)(yn - (float)yh);
    }
    LBAR();
  }
  asm volatile("s_waitcnt vmcnt(0) lgkmcnt(0)" ::: "memory");
}

extern "C" void kernel_launch(void* const* d_in, const int* in_sizes, int n_in,
                              void* d_out, int out_size, void* d_ws, size_t ws_size,
                              hipStream_t stream){
  const float* init_obs = (const float*)d_in[0];
  const float* actions  = (const float*)d_in[1];
  const float* W0 = (const float*)d_in[2];
  const float* b0 = (const float*)d_in[3];
  const float* W1 = (const float*)d_in[4];
  const float* b1 = (const float*)d_in[5];
  const float* W2 = (const float*)d_in[6];
  const float* b2 = (const float*)d_in[7];
  const float* W3 = (const float*)d_in[8];
  const float* b3 = (const float*)d_in[9];
  const int*  tau = (const int*)d_in[10];
  bf16* wsb = (bf16*)d_ws;
  float* out = (float*)d_out;

  hipLaunchKernelGGL(setup_kernel, dim3(512), dim3(256), 0, stream,
                     W0, b0, W1, W2, W3, tau, wsb);
  hipLaunchKernelGGL(ode_kernel, dim3(256), dim3(512), 0, stream,
                     init_obs, actions, b1, b2, b3, wsb, out);
}